// Round 12
// baseline (14794.649 us; speedup 1.0000x reference)
//
#include <hip/hip_runtime.h>

#define H 64
#define G4 256  // 4*H
#define HEAT 192  // heater blocks (one CU each; raise DVFS clock)

// __builtin_amdgcn_cvt_pkrtz returns a __fp16 vector; __builtin_amdgcn_fdot2
// takes _Float16 vectors. Keep both typedefs and pun through int.
typedef _Float16 f16x2 __attribute__((ext_vector_type(2)));
typedef __fp16 p16x2 __attribute__((ext_vector_type(2)));

__device__ __forceinline__ float tanh_f(float x) {
  float e = __expf(2.f * x);
  return 1.f - 2.f / (e + 1.f);
}
__device__ __forceinline__ f16x2 as_h2(int v) {
  union { int i; f16x2 h; } u; u.i = v; return u.h;
}
__device__ __forceinline__ int pack_f16(float lo, float hi) {
  union { p16x2 h; int i; } u;
  u.h = __builtin_amdgcn_cvt_pkrtz(lo, hi);
  return u.i;
}
__device__ __forceinline__ float bperm_f(int src_lane, float v) {
  return __int_as_float(
      __builtin_amdgcn_ds_bpermute(src_lane << 2, __float_as_int(v)));
}
// Workgroup barrier draining ONLY lgkmcnt (LDS); globals stay in flight.
__device__ __forceinline__ void wg_barrier() {
  asm volatile("s_waitcnt lgkmcnt(0)\n\ts_barrier" ::: "memory");
}

// Input projection, stored PRE-PERMUTED to the scan's thread layout:
// scan thread j-in-layer (w=j>>6, l=j&63) owns column (l&3)*64 + 16w+(l>>2),
// so proj thread computing original column (G,u) stores at
// pos = (u>>4)*64 + (u&15)*4 + G.  Then the scan reads xw[t*256 + j].
__global__ __launch_bounds__(G4) void proj_x(const float* __restrict__ x,
                                             const float* __restrict__ W,
                                             const float* __restrict__ b,
                                             float* __restrict__ xw) {
  const int t = blockIdx.x;
  const int j = threadIdx.x;
  const int u = j & 63, G = j >> 6;
  const int pos = ((u >> 4) << 6) | ((u & 15) << 2) | G;
  xw[(size_t)t * G4 + pos] =
      fmaf(x[2 * t], W[j], fmaf(x[2 * t + 1], W[G4 + j], b[j]));
}

// Fused 3-layer systolic LSTM scan (block 0) + DVFS heater blocks (1..HEAT).
//
// Scan structure is round-11-proven (absmax 1.95e-3): thread (L, w, l) of
// block 0 computes gate (l&3) of unit 16w+(l>>2) in layer L; z via
// uniform-address ds_read_b128 broadcast of packed-f16 h pairs + fdot2;
// unified activation; 4-lane-group gate gather via ds_bpermute; redundant
// cell update; parity double-buffered sh_hp; ONE lgkm-only barrier/step.
//
// Heater rationale: with 1 busy CU of 256, the chip sits at a DVFS
// low-clock state (measured ~850-900 MHz from VALUBusy vs instruction
// count). Heaters occupy 192 CUs with dense v_fma to pull the clock up,
// and exit when block 0 sets `flag` (plus a hard cap). The 100KB static
// LDS makes every block exclusive on its CU, so no heater can co-schedule
// with (and steal issue slots from) the scan block.
__global__ __attribute__((amdgpu_flat_work_group_size(768, 768),
                          amdgpu_waves_per_eu(3, 3)))
void fused_scan(const float* __restrict__ xw,  // [T,256] permuted x@W1+b1
                const float* __restrict__ U1,
                const float* __restrict__ W2, const float* __restrict__ U2,
                const float* __restrict__ b2,
                const float* __restrict__ W3, const float* __restrict__ U3,
                const float* __restrict__ b3,
                float* __restrict__ h3out, int* __restrict__ flag, int T) {
  __shared__ int4 sh_hp[2][3][8];  // [parity][layer][32 packed f16 h pairs]
  __shared__ char lds_pad[100 * 1024];  // CU-exclusivity pad (2x100KB>160KB)

  const int tid = (int)threadIdx.x;
  if (flag == nullptr) lds_pad[tid] = 1;  // never true; keeps pad allocated

  // ---- heater blocks ----
  if (blockIdx.x != 0) {
    float a = 1.0f + (float)(tid & 63) * 1e-6f;
    for (int it = 0; it < 400000; ++it) {  // hard cap ~64ms @2.4GHz
#pragma unroll
      for (int q = 0; q < 64; ++q) a = fmaf(a, 0.99999988f, 1.0e-7f);
      if ((it & 63) == 0) {
        if (__hip_atomic_load(flag, __ATOMIC_RELAXED,
                              __HIP_MEMORY_SCOPE_AGENT) != 0)
          break;
      }
    }
    asm volatile("" ::"v"(a));
    return;
  }

  // ---- scan block (identical to round 11) ----
  const int L = tid >> 8;   // layer (wave-uniform)
  const int j = tid & 255;  // thread-in-layer
  const int w = j >> 6;     // wave-in-layer (units 16w..16w+15)
  const int l = j & 63;     // lane
  const int G = l & 3;      // gate: 0=i,1=f,2=g(tanh),3=o
  const int u = (w << 4) | (l >> 2);  // unit
  const int col = (G << 6) | u;       // z-column in original layout

  const float* U  = (L == 0) ? U1 : ((L == 1) ? U2 : U3);
  const float* Wp = (L == 0) ? U1 : ((L == 1) ? W2 : W3);  // dummy for L0

  int upk[32], wpk[32];
#pragma unroll
  for (int k = 0; k < 32; ++k)
    upk[k] = pack_f16(U[(2 * k) * G4 + col], U[(2 * k + 1) * G4 + col]);
#pragma unroll
  for (int k = 0; k < 32; ++k)
    wpk[k] = pack_f16(Wp[(2 * k) * G4 + col], Wp[(2 * k + 1) * G4 + col]);
#pragma unroll
  for (int k = 0; k < 32; ++k) asm volatile("" : "+v"(upk[k]));
#pragma unroll
  for (int k = 0; k < 32; ++k) asm volatile("" : "+v"(wpk[k]));

  float bj = 0.f;
  if (L == 1) bj = b2[col];
  if (L == 2) bj = b3[col];

  // Unified activation: e = exp(z*esel); r = 1/(1+e); act = ka*r + kb.
  const bool is_g = (G == 2);
  const float esel = is_g ? 2.f : -1.f;
  const float ka = is_g ? -2.f : 1.f;
  const float kb = is_g ? 1.f : 0.f;

  if (tid < 48) ((int4*)sh_hp)[tid] = make_int4(0, 0, 0, 0);
  wg_barrier();

  float c = 0.f;
  float nxt = 0.f;
  if (L == 0) nxt = xw[j];  // 1-step-ahead xw prefetch (permuted layout)

  const int S = T + 2;
  for (int s = 0; s < S; ++s) {
    const int t = s - L;
    const bool active = (t >= 0) && (t < T);  // uniform within layer

    if (active) {
      const int rbuf = (s - 1) & 1;
      float z0, z1 = 0.f, z2 = 0.f, z3 = 0.f;
      if (L == 0) {
        z0 = nxt;
        const int sn = (s + 1 < T) ? (s + 1) : (T - 1);
        nxt = xw[(size_t)sn * G4 + j];  // fire-and-forget prefetch
      } else {
        z0 = bj;
      }
      const int4* hb = &sh_hp[rbuf][L][0];  // own h (uniform addr broadcast)
#pragma unroll
      for (int r = 0; r < 8; ++r) {
        const int4 hv = hb[r];
        z0 = __builtin_amdgcn_fdot2(as_h2(hv.x), as_h2(upk[4 * r]), z0, false);
        z1 = __builtin_amdgcn_fdot2(as_h2(hv.y), as_h2(upk[4 * r + 1]), z1,
                                    false);
        z2 = __builtin_amdgcn_fdot2(as_h2(hv.z), as_h2(upk[4 * r + 2]), z2,
                                    false);
        z3 = __builtin_amdgcn_fdot2(as_h2(hv.w), as_h2(upk[4 * r + 3]), z3,
                                    false);
      }
      if (L > 0) {
        const int4* pb = &sh_hp[rbuf][L - 1][0];  // prev-layer h
#pragma unroll
        for (int r = 0; r < 8; ++r) {
          const int4 hv = pb[r];
          z0 = __builtin_amdgcn_fdot2(as_h2(hv.x), as_h2(wpk[4 * r]), z0,
                                      false);
          z1 = __builtin_amdgcn_fdot2(as_h2(hv.y), as_h2(wpk[4 * r + 1]), z1,
                                      false);
          z2 = __builtin_amdgcn_fdot2(as_h2(hv.z), as_h2(wpk[4 * r + 2]), z2,
                                      false);
          z3 = __builtin_amdgcn_fdot2(as_h2(hv.w), as_h2(wpk[4 * r + 3]), z3,
                                      false);
        }
      }
      const float z = (z0 + z1) + (z2 + z3);

      const float e = __expf(z * esel);
      const float r = 1.f / (1.f + e);
      const float act = fmaf(ka, r, kb);

      const int gbase = l & ~3;
      const float gi = bperm_f(gbase + 0, act);
      const float gf = bperm_f(gbase + 1, act);
      const float gg = bperm_f(gbase + 2, act);
      const float go = bperm_f(gbase + 3, act);

      c = fmaf(gf, c, gi * gg);  // redundant in the 4-lane group
      const float h = go * tanh_f(c);
      const float hx = __shfl_xor(h, 4, 64);  // partner unit's h

      if ((l & 7) == 0)
        ((int*)&sh_hp[s & 1][L][0])[(w << 3) | (l >> 3)] = pack_f16(h, hx);
      if (L == 2 && t == T - 1 && G == 0) h3out[u] = h;
    }
    wg_barrier();  // the ONLY barrier per step
  }

  if (tid == 0)
    __hip_atomic_store(flag, 1, __ATOMIC_RELEASE, __HIP_MEMORY_SCOPE_AGENT);
}

// Dense head: relu(h3@Wd1+bd1) -> relu(@Wd2+bd2) -> @Wl+bl  (all f32)
__global__ __launch_bounds__(64) void head_k(const float* __restrict__ hlast,
                                             const float* __restrict__ Wd1,
                                             const float* __restrict__ bd1,
                                             const float* __restrict__ Wd2,
                                             const float* __restrict__ bd2,
                                             const float* __restrict__ Wl,
                                             const float* __restrict__ bl,
                                             float* __restrict__ out) {
  __shared__ float s_h[H];
  __shared__ float s_a[20];
  __shared__ float s_b[20];
  const int j = threadIdx.x;
  s_h[j] = hlast[j];
  __syncthreads();
  if (j < 20) {
    float acc = bd1[j];
#pragma unroll
    for (int k = 0; k < H; ++k) acc = fmaf(s_h[k], Wd1[k * 20 + j], acc);
    s_a[j] = fmaxf(acc, 0.f);
  }
  __syncthreads();
  if (j < 20) {
    float acc = bd2[j];
#pragma unroll
    for (int k = 0; k < 20; ++k) acc = fmaf(s_a[k], Wd2[k * 20 + j], acc);
    s_b[j] = fmaxf(acc, 0.f);
  }
  __syncthreads();
  if (j < 10) {
    float acc = bl[j];
#pragma unroll
    for (int k = 0; k < 20; ++k) acc = fmaf(s_b[k], Wl[k * 10 + j], acc);
    out[j] = acc;
  }
}

extern "C" void kernel_launch(void* const* d_in, const int* in_sizes, int n_in,
                              void* d_out, int out_size, void* d_ws, size_t ws_size,
                              hipStream_t stream) {
  const float* x   = (const float*)d_in[0];
  const float* W1  = (const float*)d_in[1];
  const float* U1  = (const float*)d_in[2];
  const float* b1  = (const float*)d_in[3];
  const float* W2  = (const float*)d_in[4];
  const float* U2  = (const float*)d_in[5];
  const float* b2  = (const float*)d_in[6];
  const float* W3  = (const float*)d_in[7];
  const float* U3  = (const float*)d_in[8];
  const float* b3  = (const float*)d_in[9];
  const float* Wd1 = (const float*)d_in[10];
  const float* bd1 = (const float*)d_in[11];
  const float* Wd2 = (const float*)d_in[12];
  const float* bd2 = (const float*)d_in[13];
  const float* Wl  = (const float*)d_in[14];
  const float* bl  = (const float*)d_in[15];
  const int T = in_sizes[0] / 2;  // 16384

  // workspace: xw [T,256] | h3 [64] | flag [1]
  float* xw = (float*)d_ws;
  float* h3 = xw + (size_t)T * G4;
  int* flag = (int*)(h3 + H);

  hipMemsetAsync(flag, 0, sizeof(int), stream);

  proj_x<<<T, G4, 0, stream>>>(x, W1, b1, xw);
  fused_scan<<<1 + HEAT, 768, 0, stream>>>(xw, U1, W2, U2, b2, W3, U3, b3, h3,
                                           flag, T);
  head_k<<<1, 64, 0, stream>>>(h3, Wd1, bd1, Wd2, bd2, Wl, bl, (float*)d_out);
}

// Round 13
// 13533.641 us; speedup vs baseline: 1.0932x; 1.0932x over previous
//
#include <hip/hip_runtime.h>

#define H 64
#define G4 256  // 4*H

typedef _Float16 f16x8 __attribute__((ext_vector_type(8)));
typedef float f32x4 __attribute__((ext_vector_type(4)));
typedef __fp16 p16x2 __attribute__((ext_vector_type(2)));

union I4F { int4 i; f16x8 h; };

__device__ __forceinline__ float sigmoid_f(float x) {
  return 1.f / (1.f + __expf(-x));
}
__device__ __forceinline__ float tanh_f(float x) {
  float e = __expf(2.f * x);
  return 1.f - 2.f / (e + 1.f);
}
__device__ __forceinline__ int pack_f16(float lo, float hi) {
  union { p16x2 h; int i; } u;
  u.h = __builtin_amdgcn_cvt_pkrtz(lo, hi);
  return u.i;
}
// Workgroup barrier draining ONLY lgkmcnt (LDS); globals stay in flight.
__device__ __forceinline__ void wg_barrier() {
  asm volatile("s_waitcnt lgkmcnt(0)\n\ts_barrier" ::: "memory");
}

// Input projection stored UNIT-MAJOR: pos = u*4 + G, so a scan lane can
// fetch all 4 gate bases of its unit as one float4.
__global__ __launch_bounds__(G4) void proj_x(const float* __restrict__ x,
                                             const float* __restrict__ W,
                                             const float* __restrict__ b,
                                             float* __restrict__ xw) {
  const int t = blockIdx.x;
  const int j = threadIdx.x;  // original column = G*64 + u
  const int G = j >> 6, u = j & 63;
  xw[(size_t)t * G4 + u * 4 + G] =
      fmaf(x[2 * t], W[j], fmaf(x[2 * t + 1], W[G4 + j], b[j]));
}

// Fused 3-layer systolic LSTM scan, ONE block, 768 threads = 3 layers x 4
// waves, MFMA dot engine. Round-12 diagnosis: the fdot2 version was
// LDS-pipe-bound (~160 ds_read_b128/step). MFMA slashes DS traffic:
//   z-slice (M=64/wave) = sum over 2 K-tiles of mfma_f32_16x16x32_f16,
//   weights as A-fragments in VGPRs, h as B replicated over all 16 columns
//   (B[k][n] = h[k] -> every lane's accums are valid z's).
// Column permutation m = uu*4 + G within each 16-row tile means (via the
// m89-verified C/D mapping row=(lane>>4)*4+reg) lane (n,kg) reg r of tile
// tau = gate r of unit 16w+4tau+kg: all 4 gates of one unit in one lane.
// A cndmask tree picks tile tsel=n&3 per lane -> each lane runs activation
// + cell for exactly ONE unit (u_own = 16w + 4*(n&3) + kg, 4x replicated).
// Publish: lanes n<4 write h as f16 via ONE masked ds_write_b16.
// DS ops/wave/step: 2 own-B reads + 2 prev-B reads (L>0) + 1 write.
// Sync: parity double-buffered sh_hp + ONE lgkm-only barrier/step (r11).
__global__ __attribute__((amdgpu_flat_work_group_size(768, 768),
                          amdgpu_waves_per_eu(3, 3)))
void fused_scan(const float* __restrict__ xw,  // [T,256] unit-major x@W1+b1
                const float* __restrict__ U1,
                const float* __restrict__ W2, const float* __restrict__ U2,
                const float* __restrict__ b2,
                const float* __restrict__ W3, const float* __restrict__ U3,
                const float* __restrict__ b3,
                float* __restrict__ h3out, int T) {
  __shared__ int4 sh_hp[2][3][8];  // [parity][layer][32 ints = 64 f16 h]

  const int tid = (int)threadIdx.x;
  const int L = tid >> 8;       // layer (wave-uniform)
  const int j = tid & 255;      // thread-in-layer
  const int wv = j >> 6;        // wave-in-layer (units 16wv..16wv+15)
  const int lane = j & 63;
  const int n = lane & 15;      // MFMA "column" lane group
  const int kg = lane >> 4;     // MFMA k-group / accum row group
  const int tsel = n & 3;       // tile this lane owns post-select
  const int u_own = (wv << 4) | (tsel << 2) | kg;  // unit in layer (0..63)

  const float* U  = (L == 0) ? U1 : ((L == 1) ? U2 : U3);
  const float* Wp = (L == 0) ? U1 : ((L == 1) ? W2 : W3);  // dummy for L0
  const float* bb = (L == 1) ? b2 : b3;

  // A-fragments (weights): tile tau, K-tile kap: lane (n,kg) holds
  // A[m=n][k=kg*8+e], A[m][k] = Umat[kap*32+k][colA(tau, m=n)],
  // colA = (n&3)*64 + 16wv + 4tau + (n>>2). Packed f16 pairs, int4 per frag.
  int4 au[4][2], aw[4][2];
#pragma unroll
  for (int tau = 0; tau < 4; ++tau) {
    const int colA = ((n & 3) << 6) | (wv << 4) | (tau << 2) | (n >> 2);
#pragma unroll
    for (int kap = 0; kap < 2; ++kap) {
      const int k0 = kap * 32 + kg * 8;
      au[tau][kap] = make_int4(
          pack_f16(U[(k0 + 0) * G4 + colA], U[(k0 + 1) * G4 + colA]),
          pack_f16(U[(k0 + 2) * G4 + colA], U[(k0 + 3) * G4 + colA]),
          pack_f16(U[(k0 + 4) * G4 + colA], U[(k0 + 5) * G4 + colA]),
          pack_f16(U[(k0 + 6) * G4 + colA], U[(k0 + 7) * G4 + colA]));
      aw[tau][kap] = make_int4(
          pack_f16(Wp[(k0 + 0) * G4 + colA], Wp[(k0 + 1) * G4 + colA]),
          pack_f16(Wp[(k0 + 2) * G4 + colA], Wp[(k0 + 3) * G4 + colA]),
          pack_f16(Wp[(k0 + 4) * G4 + colA], Wp[(k0 + 5) * G4 + colA]),
          pack_f16(Wp[(k0 + 6) * G4 + colA], Wp[(k0 + 7) * G4 + colA]));
      asm volatile("" : "+v"(au[tau][kap].x), "+v"(au[tau][kap].y),
                       "+v"(au[tau][kap].z), "+v"(au[tau][kap].w));
      asm volatile("" : "+v"(aw[tau][kap].x), "+v"(aw[tau][kap].y),
                       "+v"(aw[tau][kap].z), "+v"(aw[tau][kap].w));
    }
  }

  // Bias accumulator seeds (L>0): acc[tau] reg r = z[col r*64 + utau],
  // utau = 16wv + 4tau + kg.
  f32x4 bi[4];
#pragma unroll
  for (int tau = 0; tau < 4; ++tau) {
    const int utau = (wv << 4) | (tau << 2) | kg;
    if (L > 0)
      bi[tau] = (f32x4){bb[utau], bb[64 + utau], bb[128 + utau],
                        bb[192 + utau]};
    else
      bi[tau] = (f32x4){0.f, 0.f, 0.f, 0.f};
  }

  if (tid < 48) ((int4*)sh_hp)[tid] = make_int4(0, 0, 0, 0);
  wg_barrier();

  float c = 0.f;
  float4 nxt = make_float4(0.f, 0.f, 0.f, 0.f);
  if (L == 0) nxt = *(const float4*)(xw + u_own * 4);  // xw[0], own unit

  const int S = T + 2;
  for (int s = 0; s < S; ++s) {
    const int t = s - L;
    const bool active = (t >= 0) && (t < T);  // uniform within layer

    if (active) {
      const int rbuf = (s - 1) & 1;
      I4F b0, b1;
      b0.i = sh_hp[rbuf][L][kg];      // own h, K-tile 0 (k = kg*8..+8)
      b1.i = sh_hp[rbuf][L][4 + kg];  // own h, K-tile 1
      f32x4 a0 = bi[0], a1 = bi[1], a2 = bi[2], a3 = bi[3];
      I4F t00, t01, t10, t11, t20, t21, t30, t31;
      t00.i = au[0][0]; t01.i = au[0][1];
      t10.i = au[1][0]; t11.i = au[1][1];
      t20.i = au[2][0]; t21.i = au[2][1];
      t30.i = au[3][0]; t31.i = au[3][1];
      a0 = __builtin_amdgcn_mfma_f32_16x16x32_f16(t00.h, b0.h, a0, 0, 0, 0);
      a1 = __builtin_amdgcn_mfma_f32_16x16x32_f16(t10.h, b0.h, a1, 0, 0, 0);
      a2 = __builtin_amdgcn_mfma_f32_16x16x32_f16(t20.h, b0.h, a2, 0, 0, 0);
      a3 = __builtin_amdgcn_mfma_f32_16x16x32_f16(t30.h, b0.h, a3, 0, 0, 0);
      a0 = __builtin_amdgcn_mfma_f32_16x16x32_f16(t01.h, b1.h, a0, 0, 0, 0);
      a1 = __builtin_amdgcn_mfma_f32_16x16x32_f16(t11.h, b1.h, a1, 0, 0, 0);
      a2 = __builtin_amdgcn_mfma_f32_16x16x32_f16(t21.h, b1.h, a2, 0, 0, 0);
      a3 = __builtin_amdgcn_mfma_f32_16x16x32_f16(t31.h, b1.h, a3, 0, 0, 0);
      if (L > 0) {
        I4F p0, p1;
        p0.i = sh_hp[rbuf][L - 1][kg];
        p1.i = sh_hp[rbuf][L - 1][4 + kg];
        I4F w00, w01, w10, w11, w20, w21, w30, w31;
        w00.i = aw[0][0]; w01.i = aw[0][1];
        w10.i = aw[1][0]; w11.i = aw[1][1];
        w20.i = aw[2][0]; w21.i = aw[2][1];
        w30.i = aw[3][0]; w31.i = aw[3][1];
        a0 = __builtin_amdgcn_mfma_f32_16x16x32_f16(w00.h, p0.h, a0, 0, 0, 0);
        a1 = __builtin_amdgcn_mfma_f32_16x16x32_f16(w10.h, p0.h, a1, 0, 0, 0);
        a2 = __builtin_amdgcn_mfma_f32_16x16x32_f16(w20.h, p0.h, a2, 0, 0, 0);
        a3 = __builtin_amdgcn_mfma_f32_16x16x32_f16(w30.h, p0.h, a3, 0, 0, 0);
        a0 = __builtin_amdgcn_mfma_f32_16x16x32_f16(w01.h, p1.h, a0, 0, 0, 0);
        a1 = __builtin_amdgcn_mfma_f32_16x16x32_f16(w11.h, p1.h, a1, 0, 0, 0);
        a2 = __builtin_amdgcn_mfma_f32_16x16x32_f16(w21.h, p1.h, a2, 0, 0, 0);
        a3 = __builtin_amdgcn_mfma_f32_16x16x32_f16(w31.h, p1.h, a3, 0, 0, 0);
      }

      // Select this lane's tile (tsel = n&3): 3 cndmasks per component.
      const bool se = (tsel & 1) == 0;
      const bool s01 = (tsel & 2) == 0;
      float z0, z1, z2, z3;
      {
        float lo, hi;
        lo = se ? a0[0] : a1[0]; hi = se ? a2[0] : a3[0]; z0 = s01 ? lo : hi;
        lo = se ? a0[1] : a1[1]; hi = se ? a2[1] : a3[1]; z1 = s01 ? lo : hi;
        lo = se ? a0[2] : a1[2]; hi = se ? a2[2] : a3[2]; z2 = s01 ? lo : hi;
        lo = se ? a0[3] : a1[3]; hi = se ? a2[3] : a3[3]; z3 = s01 ? lo : hi;
      }
      if (L == 0) {
        z0 += nxt.x; z1 += nxt.y; z2 += nxt.z; z3 += nxt.w;
        const int sn = (s + 1 < T) ? (s + 1) : (T - 1);
        nxt = *(const float4*)(xw + (size_t)sn * G4 + u_own * 4);  // prefetch
      }

      const float gi = sigmoid_f(z0);
      const float gf = sigmoid_f(z1);
      const float gg = tanh_f(z2);
      const float go = sigmoid_f(z3);
      c = fmaf(gf, c, gi * gg);
      const float h = go * tanh_f(c);

      if (n < 4)  // one masked ds_write_b16: 16 lanes cover the wave's units
        ((__fp16*)&sh_hp[s & 1][L][0])[u_own] = (__fp16)h;
      if (L == 2 && t == T - 1 && n < 4) h3out[u_own] = h;
    }
    wg_barrier();  // the ONLY barrier per step
  }
}

// Dense head: relu(h3@Wd1+bd1) -> relu(@Wd2+bd2) -> @Wl+bl  (all f32)
__global__ __launch_bounds__(64) void head_k(const float* __restrict__ hlast,
                                             const float* __restrict__ Wd1,
                                             const float* __restrict__ bd1,
                                             const float* __restrict__ Wd2,
                                             const float* __restrict__ bd2,
                                             const float* __restrict__ Wl,
                                             const float* __restrict__ bl,
                                             float* __restrict__ out) {
  __shared__ float s_h[H];
  __shared__ float s_a[20];
  __shared__ float s_b[20];
  const int j = threadIdx.x;
  s_h[j] = hlast[j];
  __syncthreads();
  if (j < 20) {
    float acc = bd1[j];
#pragma unroll
    for (int k = 0; k < H; ++k) acc = fmaf(s_h[k], Wd1[k * 20 + j], acc);
    s_a[j] = fmaxf(acc, 0.f);
  }
  __syncthreads();
  if (j < 20) {
    float acc = bd2[j];
#pragma unroll
    for (int k = 0; k < 20; ++k) acc = fmaf(s_a[k], Wd2[k * 20 + j], acc);
    s_b[j] = fmaxf(acc, 0.f);
  }
  __syncthreads();
  if (j < 10) {
    float acc = bl[j];
#pragma unroll
    for (int k = 0; k < 20; ++k) acc = fmaf(s_b[k], Wl[k * 10 + j], acc);
    out[j] = acc;
  }
}

extern "C" void kernel_launch(void* const* d_in, const int* in_sizes, int n_in,
                              void* d_out, int out_size, void* d_ws, size_t ws_size,
                              hipStream_t stream) {
  const float* x   = (const float*)d_in[0];
  const float* W1  = (const float*)d_in[1];
  const float* U1  = (const float*)d_in[2];
  const float* b1  = (const float*)d_in[3];
  const float* W2  = (const float*)d_in[4];
  const float* U2  = (const float*)d_in[5];
  const float* b2  = (const float*)d_in[6];
  const float* W3  = (const float*)d_in[7];
  const float* U3  = (const float*)d_in[8];
  const float* b3  = (const float*)d_in[9];
  const float* Wd1 = (const float*)d_in[10];
  const float* bd1 = (const float*)d_in[11];
  const float* Wd2 = (const float*)d_in[12];
  const float* bd2 = (const float*)d_in[13];
  const float* Wl  = (const float*)d_in[14];
  const float* bl  = (const float*)d_in[15];
  const int T = in_sizes[0] / 2;  // 16384

  // workspace: xw [T,256] | h3 [64]
  float* xw = (float*)d_ws;
  float* h3 = xw + (size_t)T * G4;

  proj_x<<<T, G4, 0, stream>>>(x, W1, b1, xw);
  fused_scan<<<1, 768, 0, stream>>>(xw, U1, W2, U2, b2, W3, U3, b3, h3, T);
  head_k<<<1, 64, 0, stream>>>(h3, Wd1, bd1, Wd2, bd2, Wl, bl, (float*)d_out);
}